// Round 9
// baseline (194.370 us; speedup 1.0000x reference)
//
#include <hip/hip_runtime.h>
#include <hip/hip_bf16.h>

// RecursiveNN, perfect binary tree. N=262144 leaves, IN=64, HID=128.
// SETTLED: inputs fp32 jax-layout ([K,N] weights), output fp32[128].
// R8 passed at 174.6us: kfront 82us (VALU-bound: VALUBusy 60%, MfmaUtil 13%,
// occupancy 20% w/ launch_bounds(256,2)); tail kmid+ktail ~92us dominated by
// per-lane 128-scalar-load weight gather at no-occupancy latency.
// R9: (1) kmid/ktail weights via coalesced float4 -> transposed LDS
// ([n][k] stride 136, aligned b128 frag reads); (2) kfront 3 blocks/CU;
// (3) cheaper tanh (v_exp+v_rcp) + packed bf16 cvt (v_cvt_pk_bf16_f32).
//
// Structure (3 launches, in-place in leaf_x buffer XB, no d_ws):
//  kfront: 2048 blocks, 128-leaf subtree: leaf GEMM + levels 1..7 (MFMA),
//          writes 1 fp32 row at XB[8192*b] (own consumed region).
//  kmid:   16 blocks: gather 128 rows, levels 8..14, row -> XB[1048576*t+4096].
//  ktail:  1 block: 16 rows, levels 15..18, root fp32 -> d_out.
// H LDS layout: row stride 136 bf16, col swizzle c ^ (((row>>3)&3)<<3).

typedef unsigned short u16;
typedef unsigned int u32;
typedef __attribute__((ext_vector_type(8))) short bf16x8;   // 8 bf16, 4 VGPR
typedef __attribute__((ext_vector_type(4))) float f32x4;

__device__ __forceinline__ float bf2f(u16 u) {
    union { u32 i; float f; } c; c.i = ((u32)u) << 16; return c.f;
}
__device__ __forceinline__ u16 f2bf(float f) {
    __hip_bfloat16 h = __float2bfloat16(f);   // RNE
    return *(u16*)&h;
}
// packed RNE cvt: lo16 = bf16(a), hi16 = bf16(b)  (v_cvt_pk_bf16_f32)
__device__ __forceinline__ u32 f2bf_pk(float a, float b) {
    __hip_bfloat162 h = __float22bfloat162_rn(make_float2(a, b));
    return *(u32*)&h;
}
// NaN-free tanh: 1 - 2/(2^(x*2log2e)+1); exp/rcp HW approx (~1ulp, << bf16)
__device__ __forceinline__ float fast_tanh(float x) {
#if __has_builtin(__builtin_amdgcn_exp2f) && __has_builtin(__builtin_amdgcn_rcpf)
    float t = __builtin_amdgcn_exp2f(x * 2.8853900817779268f);
    float r = __builtin_amdgcn_rcpf(t + 1.0f);
    return __builtin_fmaf(-2.0f, r, 1.0f);
#else
    float e = __expf(2.0f * x);
    return 1.0f - 2.0f / (e + 1.0f);
#endif
}
__device__ __forceinline__ int swz(int row, int c) {
    return c ^ (((row >> 3) & 3) << 3);
}

#define MFMA16(a, b, c) __builtin_amdgcn_mfma_f32_16x16x32_bf16((a), (b), (c), 0, 0, 0)

// ---- B-frags via global scalar gather (kfront only; amortized, L2-hot) -----
__device__ __forceinline__ void load_level_frags_g(
    const float* __restrict__ Wl, const float* __restrict__ Wr,
    int w, int quad, int lq, bf16x8 (&bw)[8][2]) {
    const int n0 = 32 * w + lq, n1 = n0 + 16;
#pragma unroll
    for (int kc = 0; kc < 8; ++kc) {
        const float* W = (kc < 4) ? Wl : Wr;
        const int kb = (kc & 3) * 32 + quad * 8;
        bf16x8 f0, f1;
#pragma unroll
        for (int j = 0; j < 8; ++j) {
            const float* rowp = W + (size_t)(kb + j) * 128;
            f0[j] = (short)f2bf(rowp[n0]);
            f1[j] = (short)f2bf(rowp[n1]);
        }
        bw[kc][0] = f0; bw[kc][1] = f1;
    }
}

// ---- W -> transposed LDS (kmid/ktail): Wt[mat][n][k], stride 136 -----------
__device__ __forceinline__ void stage_w_t(u16* Wt, const float* __restrict__ Wl,
                                          const float* __restrict__ Wr, int tid) {
#pragma unroll
    for (int t = 0; t < 32; ++t) {
        int i4 = tid + 256 * t;                    // 0..8191
        const float* W = (i4 < 4096) ? Wl : Wr;
        u16* dst = Wt + ((i4 < 4096) ? 0 : 128 * 136);
        int rem = i4 & 4095;
        int k = rem >> 5;                          // 0..127
        int n4 = (rem & 31) << 2;                  // 0..124
        float4 v = *(const float4*)(W + (size_t)k * 128 + n4);
        dst[(n4 + 0) * 136 + k] = f2bf(v.x);
        dst[(n4 + 1) * 136 + k] = f2bf(v.y);
        dst[(n4 + 2) * 136 + k] = f2bf(v.z);
        dst[(n4 + 3) * 136 + k] = f2bf(v.w);
    }
}
__device__ __forceinline__ void load_level_frags_lds(
    const u16* Wt, int w, int quad, int lq, bf16x8 (&bw)[8][2]) {
    const int n0 = 32 * w + lq, n1 = n0 + 16;
#pragma unroll
    for (int kc = 0; kc < 8; ++kc) {
        const int base = (kc < 4) ? 0 : 128 * 136;
        const int kb = (kc & 3) * 32 + quad * 8;
        bw[kc][0] = *(const bf16x8*)(Wt + base + n0 * 136 + kb);
        bw[kc][1] = *(const bf16x8*)(Wt + base + n1 * 136 + kb);
    }
}

// ---- pairwise levels: in-buffer 2*Mfirst rows -> ... -> 1 row --------------
__device__ __forceinline__ void run_levels_mfma(
    u16* b0, u16* b1, int Mfirst, const bf16x8 (&bw)[8][2],
    float bs0, float bs1, float* finalOut, int w, int quad, int lq) {
    const int co0 = 32 * w + lq, co1 = co0 + 16;
    u16* in = b0;
    u16* out = b1;
    for (int M = Mfirst; M >= 1; M >>= 1) {
        const int ntiles = (M + 15) >> 4;
        for (int rt = 0; rt < ntiles; ++rt) {
            const int r0e = rt * 16;
            bf16x8 a[8];
#pragma unroll
            for (int kc = 0; kc < 8; ++kc) {
                const int row = 2 * (r0e + lq) + (kc >> 2);
                const int kb = (kc & 3) * 32 + quad * 8;
                a[kc] = *(const bf16x8*)(in + row * 136 + swz(row, kb));
            }
            f32x4 ac0 = {0.f, 0.f, 0.f, 0.f}, ac1 = {0.f, 0.f, 0.f, 0.f};
#pragma unroll
            for (int kc = 0; kc < 8; ++kc) {
                ac0 = MFMA16(a[kc], bw[kc][0], ac0);
                ac1 = MFMA16(a[kc], bw[kc][1], ac1);
            }
#pragma unroll
            for (int r = 0; r < 4; ++r) {
                const int ro = r0e + quad * 4 + r;
                if (ro < M) {
                    float v0 = fast_tanh(ac0[r] + bs0);
                    float v1 = fast_tanh(ac1[r] + bs1);
                    if (M == 1 && finalOut) {        // ro==0 here
                        finalOut[co0] = v0;
                        finalOut[co1] = v1;
                    } else {
                        u32 pk = f2bf_pk(v0, v1);
                        out[ro * 136 + swz(ro, co0)] = (u16)pk;
                        out[ro * 136 + swz(ro, co1)] = (u16)(pk >> 16);
                    }
                }
            }
        }
        __syncthreads();
        u16* t = in; in = out; out = t;
    }
}

// ---- kfront: leaf GEMM + levels 1..7 for a 128-leaf subtree ----------------
__global__ __launch_bounds__(256, 3) void kfront(
    float* XB, const float* __restrict__ Win, const float* __restrict__ bin,
    const float* __restrict__ Wl, const float* __restrict__ Wr,
    const float* __restrict__ bl, const float* __restrict__ br) {
    __shared__ __align__(16) u16 H0[128 * 136];   // 34816 B
    __shared__ __align__(16) u16 POOL[128 * 72];  // 18432 B: Xa, then H1
    // 53248 B total -> 3 blocks/CU

    const int tid = threadIdx.x;
    const int w = tid >> 6, lane = tid & 63, quad = lane >> 4, lq = lane & 15;
    const int b = blockIdx.x;
    u16* Xa = POOL;   // [128][72] bf16 leaf inputs
    u16* H1 = POOL;   // [64][136] after leaf phase (Xa dead)

    const float* Xg = XB + (size_t)b * 8192;      // 128 rows x 64
#pragma unroll
    for (int t = 0; t < 8; ++t) {
        int i4 = tid + 256 * t;
        int r = i4 >> 4, k4 = (i4 & 15) << 2;
        float4 v = *(const float4*)(Xg + r * 64 + k4);
        *(uint2*)(Xa + r * 72 + k4) =
            make_uint2(f2bf_pk(v.x, v.y), f2bf_pk(v.z, v.w));
    }

    const int n0 = 32 * w + lq, n1 = n0 + 16;
    bf16x8 bwin[2][2];
#pragma unroll
    for (int kc = 0; kc < 2; ++kc) {
        bf16x8 f0, f1;
#pragma unroll
        for (int j = 0; j < 8; ++j) {
            const float* rowp = Win + (size_t)(kc * 32 + quad * 8 + j) * 128;
            f0[j] = (short)f2bf(rowp[n0]);
            f1[j] = (short)f2bf(rowp[n1]);
        }
        bwin[kc][0] = f0; bwin[kc][1] = f1;
    }
    bf16x8 bw[8][2];
    load_level_frags_g(Wl, Wr, w, quad, lq, bw);
    const float bin0 = bin[n0], bin1 = bin[n1];
    const float bs0 = bl[n0] + br[n0], bs1 = bl[n1] + br[n1];
    __syncthreads();

    // leaf GEMM: [128x64] @ [64x128], 8 row-tiles, K=64 = 2 MFMA per acc
    for (int rt = 0; rt < 8; ++rt) {
        const int r0e = rt * 16;
        const int rowa = r0e + lq;
        bf16x8 a0 = *(const bf16x8*)(Xa + rowa * 72 + quad * 8);
        bf16x8 a1 = *(const bf16x8*)(Xa + rowa * 72 + 32 + quad * 8);
        f32x4 ac0 = {0.f, 0.f, 0.f, 0.f}, ac1 = {0.f, 0.f, 0.f, 0.f};
        ac0 = MFMA16(a0, bwin[0][0], ac0);
        ac0 = MFMA16(a1, bwin[1][0], ac0);
        ac1 = MFMA16(a0, bwin[0][1], ac1);
        ac1 = MFMA16(a1, bwin[1][1], ac1);
#pragma unroll
        for (int r = 0; r < 4; ++r) {
            const int ro = r0e + quad * 4 + r;
            u32 pk = f2bf_pk(fast_tanh(ac0[r] + bin0), fast_tanh(ac1[r] + bin1));
            H0[ro * 136 + swz(ro, n0)] = (u16)pk;
            H0[ro * 136 + swz(ro, n1)] = (u16)(pk >> 16);
        }
    }
    __syncthreads();   // H0 complete; Xa reads done (H1 aliases Xa)

    run_levels_mfma(H0, H1, 64, bw, bs0, bs1, XB + (size_t)b * 8192,
                    w, quad, lq);
}

// ---- kmid: gather 128 subtree roots, levels 8..14 --------------------------
__global__ __launch_bounds__(256) void kmid(
    float* XB, const float* __restrict__ Wl, const float* __restrict__ Wr,
    const float* __restrict__ bl, const float* __restrict__ br) {
    __shared__ __align__(16) u16 H0[128 * 136];
    __shared__ __align__(16) u16 H1[64 * 136];
    __shared__ __align__(16) u16 Wt[2 * 128 * 136];   // 69632 B

    const int tid = threadIdx.x;
    const int w = tid >> 6, lane = tid & 63, quad = lane >> 4, lq = lane & 15;
    const int t = blockIdx.x;

    stage_w_t(Wt, Wl, Wr, tid);
#pragma unroll
    for (int it = 0; it < 16; ++it) {
        int i4 = tid + 256 * it;
        int r = i4 >> 5, k4 = (i4 & 31) << 2;
        float4 v = *(const float4*)(XB + (size_t)8192 * (128 * t + r) + k4);
        *(uint2*)(H0 + r * 136 + swz(r, k4)) =
            make_uint2(f2bf_pk(v.x, v.y), f2bf_pk(v.z, v.w));
    }
    const int n0 = 32 * w + lq, n1 = n0 + 16;
    const float bs0 = bl[n0] + br[n0], bs1 = bl[n1] + br[n1];
    __syncthreads();

    bf16x8 bw[8][2];
    load_level_frags_lds(Wt, w, quad, lq, bw);

    run_levels_mfma(H0, H1, 64, bw, bs0, bs1,
                    XB + (size_t)8192 * 128 * t + 4096, w, quad, lq);
}

// ---- ktail: 16 rows -> levels 15..18 -> root fp32 --------------------------
__global__ __launch_bounds__(256) void ktail(
    const float* XB, const float* __restrict__ Wl, const float* __restrict__ Wr,
    const float* __restrict__ bl, const float* __restrict__ br,
    float* __restrict__ out) {
    __shared__ __align__(16) u16 H0[64 * 136];
    __shared__ __align__(16) u16 H1[64 * 136];
    __shared__ __align__(16) u16 Wt[2 * 128 * 136];

    const int tid = threadIdx.x;
    const int w = tid >> 6, lane = tid & 63, quad = lane >> 4, lq = lane & 15;

    for (int i = tid; i < 64 * 136; i += 256) { H0[i] = 0; H1[i] = 0; }
    __syncthreads();   // zeros visible before staging overwrites

    stage_w_t(Wt, Wl, Wr, tid);
#pragma unroll
    for (int it = 0; it < 2; ++it) {
        int i4 = tid + 256 * it;
        int r = i4 >> 5, k4 = (i4 & 31) << 2;     // r = 0..15
        float4 v = *(const float4*)(XB + (size_t)8192 * 128 * r + 4096 + k4);
        *(uint2*)(H0 + r * 136 + swz(r, k4)) =
            make_uint2(f2bf_pk(v.x, v.y), f2bf_pk(v.z, v.w));
    }
    const int n0 = 32 * w + lq, n1 = n0 + 16;
    const float bs0 = bl[n0] + br[n0], bs1 = bl[n1] + br[n1];
    __syncthreads();

    bf16x8 bw[8][2];
    load_level_frags_lds(Wt, w, quad, lq, bw);

    run_levels_mfma(H0, H1, 8, bw, bs0, bs1, out, w, quad, lq);
}

// ---- host ------------------------------------------------------------------
extern "C" void kernel_launch(void* const* d_in, const int* in_sizes, int n_in,
                              void* d_out, int out_size, void* d_ws, size_t ws_size,
                              hipStream_t stream) {
    float* XB = (float*)d_in[0];              // consumed then reused in-place
    const float* Win = (const float*)d_in[1];
    const float* bin = (const float*)d_in[2];
    const float* Wl  = (const float*)d_in[3];
    const float* bl  = (const float*)d_in[4];
    const float* Wr  = (const float*)d_in[5];
    const float* br  = (const float*)d_in[6];
    float* out = (float*)d_out;

    kfront<<<2048, 256, 0, stream>>>(XB, Win, bin, Wl, Wr, bl, br);
    kmid<<<16, 256, 0, stream>>>(XB, Wl, Wr, bl, br);
    ktail<<<1, 256, 0, stream>>>(XB, Wl, Wr, bl, br, out);
}

// Round 10
// 168.515 us; speedup vs baseline: 1.1534x; 1.1534x over previous
//
#include <hip/hip_runtime.h>
#include <hip/hip_bf16.h>

// RecursiveNN, perfect binary tree. N=262144 leaves, IN=64, HID=128.
// SETTLED: inputs fp32 jax-layout ([K,N] weights), output fp32[128].
// R8: 174.6us (kfront 82, VGPR 128, no spill). R9 REGRESSION: launch_bounds
// (256,3) forced VGPR 84 -> scratch spills (WRITE_SIZE 1->56MB) -> 194us.
// R10: revert to (256,2); pair-column frag mapping (lane owns cols c,c+1 ->
// packed u32 epilogue stores, float2 W-gather); kfront early-stops at M=4
// (drops near-empty M=2,1 tiles); kmid 64 blocks levels 6..12; ktail 13..18.
//
// In-place in leaf_x buffer XB (no d_ws):
//  kfront b: leaf GEMM + levels 1..5 on 128 leaves -> 4 fp32 rows at
//            XB[8192b + {0..3}*128] (own consumed region).
//  kmid t (64 blocks): gather 128 rows from kfront blocks 32t..32t+31,
//            levels 6..12 -> 1 row at XB[262144t + 512].
//  ktail: 64 rows -> levels 13..18 -> root fp32[128] -> d_out.
// H LDS: row stride 136 bf16, col swizzle c ^ (((row>>3)&3)<<3).

typedef unsigned short u16;
typedef unsigned int u32;
typedef __attribute__((ext_vector_type(8))) short bf16x8;   // 8 bf16, 4 VGPR
typedef __attribute__((ext_vector_type(4))) float f32x4;

__device__ __forceinline__ u16 f2bf(float f) {
    __hip_bfloat16 h = __float2bfloat16(f);   // RNE
    return *(u16*)&h;
}
// packed RNE cvt: lo16 = bf16(a), hi16 = bf16(b)
__device__ __forceinline__ u32 f2bf_pk(float a, float b) {
    __hip_bfloat162 h = __float22bfloat162_rn(make_float2(a, b));
    return *(u32*)&h;
}
// NaN-free tanh via HW exp2/rcp
__device__ __forceinline__ float fast_tanh(float x) {
#if __has_builtin(__builtin_amdgcn_exp2f) && __has_builtin(__builtin_amdgcn_rcpf)
    float t = __builtin_amdgcn_exp2f(x * 2.8853900817779268f);
    float r = __builtin_amdgcn_rcpf(t + 1.0f);
    return __builtin_fmaf(-2.0f, r, 1.0f);
#else
    float e = __expf(2.0f * x);
    return 1.0f - 2.0f / (e + 1.0f);
#endif
}
__device__ __forceinline__ int swz(int row, int c) {
    return c ^ (((row >> 3) & 3) << 3);
}

#define MFMA16(a, b, c) __builtin_amdgcn_mfma_f32_16x16x32_bf16((a), (b), (c), 0, 0, 0)

// ---- B-frag pair from global W: tile0 lane lq = col c0=32w+2lq, tile1 c0+1.
__device__ __forceinline__ void pair_frags_g(const float* __restrict__ W,
                                             int kbase, int c0,
                                             bf16x8& f0, bf16x8& f1) {
#pragma unroll
    for (int j = 0; j < 8; ++j) {
        float2 v = *(const float2*)(W + (size_t)(kbase + j) * 128 + c0);
        f0[j] = (short)f2bf(v.x);
        f1[j] = (short)f2bf(v.y);
    }
}
__device__ __forceinline__ void load_level_frags_g(
    const float* __restrict__ Wl, const float* __restrict__ Wr,
    int quad, int c0, bf16x8 (&bw)[8][2]) {
#pragma unroll
    for (int kc = 0; kc < 8; ++kc) {
        const float* W = (kc < 4) ? Wl : Wr;
        pair_frags_g(W, (kc & 3) * 32 + quad * 8, c0, bw[kc][0], bw[kc][1]);
    }
}

// ---- W -> transposed LDS (kmid/ktail): Wt[mat][n][k], stride 136 -----------
__device__ __forceinline__ void stage_w_t(u16* Wt, const float* __restrict__ Wl,
                                          const float* __restrict__ Wr, int tid) {
#pragma unroll
    for (int t = 0; t < 32; ++t) {
        int i4 = tid + 256 * t;                    // 0..8191
        const float* W = (i4 < 4096) ? Wl : Wr;
        u16* dst = Wt + ((i4 < 4096) ? 0 : 128 * 136);
        int rem = i4 & 4095;
        int k = rem >> 5;                          // 0..127
        int n4 = (rem & 31) << 2;                  // 0..124
        float4 v = *(const float4*)(W + (size_t)k * 128 + n4);
        dst[(n4 + 0) * 136 + k] = f2bf(v.x);
        dst[(n4 + 1) * 136 + k] = f2bf(v.y);
        dst[(n4 + 2) * 136 + k] = f2bf(v.z);
        dst[(n4 + 3) * 136 + k] = f2bf(v.w);
    }
}
__device__ __forceinline__ void load_level_frags_lds(
    const u16* Wt, int quad, int c0, bf16x8 (&bw)[8][2]) {
#pragma unroll
    for (int kc = 0; kc < 8; ++kc) {
        const int base = (kc < 4) ? 0 : 128 * 136;
        const int kb = (kc & 3) * 32 + quad * 8;
        bw[kc][0] = *(const bf16x8*)(Wt + base + c0 * 136 + kb);
        bw[kc][1] = *(const bf16x8*)(Wt + base + (c0 + 1) * 136 + kb);
    }
}

// ---- pairwise levels: Mfirst..Mlast; at M==Mlast write fp32 rows to out ----
__device__ __forceinline__ void run_levels_mfma(
    u16* b0, u16* b1, int Mfirst, int Mlast, const bf16x8 (&bw)[8][2],
    float bs0, float bs1, float* finalOut, int quad, int lq, int c0) {
    u16* in = b0;
    u16* out = b1;
    for (int M = Mfirst; M >= Mlast; M >>= 1) {
        const int ntiles = (M + 15) >> 4;
        for (int rt = 0; rt < ntiles; ++rt) {
            const int r0e = rt * 16;
            bf16x8 a[8];
#pragma unroll
            for (int kc = 0; kc < 8; ++kc) {
                const int row = 2 * (r0e + lq) + (kc >> 2);
                const int kb = (kc & 3) * 32 + quad * 8;
                a[kc] = *(const bf16x8*)(in + row * 136 + swz(row, kb));
            }
            f32x4 ac0 = {0.f, 0.f, 0.f, 0.f}, ac1 = {0.f, 0.f, 0.f, 0.f};
#pragma unroll
            for (int kc = 0; kc < 8; ++kc) {
                ac0 = MFMA16(a[kc], bw[kc][0], ac0);
                ac1 = MFMA16(a[kc], bw[kc][1], ac1);
            }
#pragma unroll
            for (int r = 0; r < 4; ++r) {
                const int ro = r0e + quad * 4 + r;
                if (ro < M) {
                    float v0 = fast_tanh(ac0[r] + bs0);
                    float v1 = fast_tanh(ac1[r] + bs1);
                    if (M == Mlast) {
                        *(float2*)(finalOut + ro * 128 + c0) = make_float2(v0, v1);
                    } else {
                        *(u32*)(out + ro * 136 + swz(ro, c0)) = f2bf_pk(v0, v1);
                    }
                }
            }
        }
        __syncthreads();
        u16* t = in; in = out; out = t;
    }
}

// ---- kfront: leaf GEMM + levels 1..5 for a 128-leaf subtree ----------------
__global__ __launch_bounds__(256, 2) void kfront(
    float* XB, const float* __restrict__ Win, const float* __restrict__ bin,
    const float* __restrict__ Wl, const float* __restrict__ Wr,
    const float* __restrict__ bl, const float* __restrict__ br) {
    __shared__ __align__(16) u16 H0[128 * 136];   // 34816 B
    __shared__ __align__(16) u16 POOL[128 * 72];  // 18432 B: Xa, then H1
    // 53248 B total; VGPR 128 (no spill) -> up to 3 blocks/CU by LDS

    const int tid = threadIdx.x;
    const int w = tid >> 6, lane = tid & 63, quad = lane >> 4, lq = lane & 15;
    const int b = blockIdx.x;
    const int c0 = 32 * w + 2 * lq;               // pair (c0, c0+1)
    u16* Xa = POOL;   // [128][72] bf16 leaf inputs
    u16* H1 = POOL;   // [64][136] after leaf phase (Xa dead)

    const float* Xg = XB + (size_t)b * 8192;      // 128 rows x 64
#pragma unroll
    for (int t = 0; t < 8; ++t) {
        int i4 = tid + 256 * t;
        int r = i4 >> 4, k4 = (i4 & 15) << 2;
        float4 v = *(const float4*)(Xg + r * 64 + k4);
        *(uint2*)(Xa + r * 72 + k4) =
            make_uint2(f2bf_pk(v.x, v.y), f2bf_pk(v.z, v.w));
    }

    bf16x8 bwin[2][2];
#pragma unroll
    for (int kc = 0; kc < 2; ++kc)
        pair_frags_g(Win, kc * 32 + quad * 8, c0, bwin[kc][0], bwin[kc][1]);
    bf16x8 bw[8][2];
    load_level_frags_g(Wl, Wr, quad, c0, bw);

    const float2 binp = *(const float2*)(bin + c0);
    const float2 blp = *(const float2*)(bl + c0);
    const float2 brp = *(const float2*)(br + c0);
    const float bs0 = blp.x + brp.x, bs1 = blp.y + brp.y;
    __syncthreads();

    // leaf GEMM: [128x64] @ [64x128], 8 row-tiles, K=64 = 2 MFMA per acc
    for (int rt = 0; rt < 8; ++rt) {
        const int r0e = rt * 16;
        const int rowa = r0e + lq;
        bf16x8 a0 = *(const bf16x8*)(Xa + rowa * 72 + quad * 8);
        bf16x8 a1 = *(const bf16x8*)(Xa + rowa * 72 + 32 + quad * 8);
        f32x4 ac0 = {0.f, 0.f, 0.f, 0.f}, ac1 = {0.f, 0.f, 0.f, 0.f};
        ac0 = MFMA16(a0, bwin[0][0], ac0);
        ac0 = MFMA16(a1, bwin[1][0], ac0);
        ac1 = MFMA16(a0, bwin[0][1], ac1);
        ac1 = MFMA16(a1, bwin[1][1], ac1);
#pragma unroll
        for (int r = 0; r < 4; ++r) {
            const int ro = r0e + quad * 4 + r;
            *(u32*)(H0 + ro * 136 + swz(ro, c0)) =
                f2bf_pk(fast_tanh(ac0[r] + binp.x), fast_tanh(ac1[r] + binp.y));
        }
    }
    __syncthreads();   // H0 complete; Xa reads done (H1 aliases Xa)

    // levels 1..5 (M=64..4); write 4 fp32 rows into own region
    run_levels_mfma(H0, H1, 64, 4, bw, bs0, bs1, XB + (size_t)b * 8192,
                    quad, lq, c0);
}

// ---- kmid: 64 blocks, gather 128 rows, levels 6..12 -> 1 row ---------------
__global__ __launch_bounds__(256) void kmid(
    float* XB, const float* __restrict__ Wl, const float* __restrict__ Wr,
    const float* __restrict__ bl, const float* __restrict__ br) {
    __shared__ __align__(16) u16 H0[128 * 136];
    __shared__ __align__(16) u16 H1[64 * 136];
    __shared__ __align__(16) u16 Wt[2 * 128 * 136];   // 69632 B

    const int tid = threadIdx.x;
    const int w = tid >> 6, lane = tid & 63, quad = lane >> 4, lq = lane & 15;
    const int t = blockIdx.x;
    const int c0 = 32 * w + 2 * lq;

    stage_w_t(Wt, Wl, Wr, tid);
    // 128 rows: kfront block 32t+(r>>2), sub-row r&3
#pragma unroll
    for (int it = 0; it < 16; ++it) {
        int i4 = tid + 256 * it;
        int r = i4 >> 5, k4 = (i4 & 31) << 2;
        const float* src = XB + (size_t)8192 * (32 * t + (r >> 2)) + (r & 3) * 128 + k4;
        float4 v = *(const float4*)src;
        *(uint2*)(H0 + r * 136 + swz(r, k4)) =
            make_uint2(f2bf_pk(v.x, v.y), f2bf_pk(v.z, v.w));
    }
    const float2 blp = *(const float2*)(bl + c0);
    const float2 brp = *(const float2*)(br + c0);
    const float bs0 = blp.x + brp.x, bs1 = blp.y + brp.y;
    __syncthreads();

    bf16x8 bw[8][2];
    load_level_frags_lds(Wt, quad, c0, bw);

    run_levels_mfma(H0, H1, 64, 1, bw, bs0, bs1,
                    XB + (size_t)262144 * t + 512, quad, lq, c0);
}

// ---- ktail: 64 rows -> levels 13..18 -> root fp32 --------------------------
__global__ __launch_bounds__(256) void ktail(
    const float* XB, const float* __restrict__ Wl, const float* __restrict__ Wr,
    const float* __restrict__ bl, const float* __restrict__ br,
    float* __restrict__ out) {
    __shared__ __align__(16) u16 H0[64 * 136];
    __shared__ __align__(16) u16 H1[64 * 136];
    __shared__ __align__(16) u16 Wt[2 * 128 * 136];

    const int tid = threadIdx.x;
    const int w = tid >> 6, lane = tid & 63, quad = lane >> 4, lq = lane & 15;
    const int c0 = 32 * w + 2 * lq;

    stage_w_t(Wt, Wl, Wr, tid);
    // 64 rows from XB[262144*r + 512]
#pragma unroll
    for (int it = 0; it < 8; ++it) {
        int i4 = tid + 256 * it;
        int r = i4 >> 5, k4 = (i4 & 31) << 2;     // r = 0..63
        float4 v = *(const float4*)(XB + (size_t)262144 * r + 512 + k4);
        *(uint2*)(H0 + r * 136 + swz(r, k4)) =
            make_uint2(f2bf_pk(v.x, v.y), f2bf_pk(v.z, v.w));
    }
    const float2 blp = *(const float2*)(bl + c0);
    const float2 brp = *(const float2*)(br + c0);
    const float bs0 = blp.x + brp.x, bs1 = blp.y + brp.y;
    __syncthreads();

    bf16x8 bw[8][2];
    load_level_frags_lds(Wt, quad, c0, bw);

    run_levels_mfma(H0, H1, 32, 1, bw, bs0, bs1, out, quad, lq, c0);
}

// ---- host ------------------------------------------------------------------
extern "C" void kernel_launch(void* const* d_in, const int* in_sizes, int n_in,
                              void* d_out, int out_size, void* d_ws, size_t ws_size,
                              hipStream_t stream) {
    float* XB = (float*)d_in[0];              // consumed then reused in-place
    const float* Win = (const float*)d_in[1];
    const float* bin = (const float*)d_in[2];
    const float* Wl  = (const float*)d_in[3];
    const float* bl  = (const float*)d_in[4];
    const float* Wr  = (const float*)d_in[5];
    const float* br  = (const float*)d_in[6];
    float* out = (float*)d_out;

    kfront<<<2048, 256, 0, stream>>>(XB, Win, bin, Wl, Wr, bl, br);
    kmid<<<64, 256, 0, stream>>>(XB, Wl, Wr, bl, br);
    ktail<<<1, 256, 0, stream>>>(XB, Wl, Wr, bl, br, out);
}